// Round 6
// baseline (313.543 us; speedup 1.0000x reference)
//
#include <hip/hip_runtime.h>
#include <hip/hip_bf16.h>
#include <stdint.h>

// x[4,2048,4096] f32, qweight[4096,4096] i32, scale/zp f32 scalars, bias[4096] f32
// out = x @ (scale*(q-zp))^T + bias : M=8192, N=4096, K=4096, f32 out.
#define M_DIM 8192
#define N_DIM 4096
#define K_DIM 4096

typedef __attribute__((ext_vector_type(8))) __bf16 bf16x8;
typedef __attribute__((ext_vector_type(4))) float f32x4;
typedef __attribute__((ext_vector_type(16))) float f32x16;
typedef __attribute__((ext_vector_type(8))) unsigned short ushort8;

__device__ __forceinline__ unsigned short f2bf(float f) {
  union { float f; uint32_t u; } v; v.f = f;
  uint32_t u = v.u;
  return (unsigned short)((u + 0x7FFFu + ((u >> 16) & 1u)) >> 16);  // RNE
}

__device__ __forceinline__ void gload_lds16(const void* g, void* l) {
  __builtin_amdgcn_global_load_lds((const __attribute__((address_space(1))) void*)g,
                                   (__attribute__((address_space(3))) void*)l,
                                   16, 0, 0);
}

#define RAW_BAR() asm volatile("s_barrier" ::: "memory")
#define VMW(n) asm volatile("s_waitcnt vmcnt(" #n ")" ::: "memory")
#define LGKM0()                                        \
  do {                                                 \
    asm volatile("s_waitcnt lgkmcnt(0)" ::: "memory"); \
    __builtin_amdgcn_sched_barrier(0);                 \
  } while (0)
#define NOOP do {} while (0)

// ---- prepack kernels ----
__global__ void cvt_x_kernel(const float* __restrict__ x, unsigned short* __restrict__ xb,
                             long long n8) {
  long long i = (long long)blockIdx.x * blockDim.x + threadIdx.x;
  long long stride = (long long)gridDim.x * blockDim.x;
  for (; i < n8; i += stride) {
    const float4* p = (const float4*)x + i * 2;
    float4 a = p[0], b = p[1];
    ushort8 u;
    u[0] = f2bf(a.x); u[1] = f2bf(a.y); u[2] = f2bf(a.z); u[3] = f2bf(a.w);
    u[4] = f2bf(b.x); u[5] = f2bf(b.y); u[6] = f2bf(b.z); u[7] = f2bf(b.w);
    *(ushort8*)(xb + i * 8) = u;
  }
}

__global__ void dequant_w_kernel(const int* __restrict__ q, const float* __restrict__ scale,
                                 const float* __restrict__ zp, unsigned short* __restrict__ wb,
                                 long long n8) {
  float s = scale[0], z = zp[0];
  long long i = (long long)blockIdx.x * blockDim.x + threadIdx.x;
  long long stride = (long long)gridDim.x * blockDim.x;
  for (; i < n8; i += stride) {
    const int4* p = (const int4*)q + i * 2;
    int4 a = p[0], b = p[1];
    ushort8 u;
    u[0] = f2bf(s * ((float)a.x - z)); u[1] = f2bf(s * ((float)a.y - z));
    u[2] = f2bf(s * ((float)a.z - z)); u[3] = f2bf(s * ((float)a.w - z));
    u[4] = f2bf(s * ((float)b.x - z)); u[5] = f2bf(s * ((float)b.y - z));
    u[6] = f2bf(s * ((float)b.z - z)); u[7] = f2bf(s * ((float)b.w - z));
    *(ushort8*)(wb + i * 8) = u;
  }
}

// ---- main GEMM: 8-phase template (round-5 skeleton), 32x32x16 MFMA quadrants.
// 256x256 tile, BK=64, 8 waves (2Mx4N, 128x64/wave).
// LDS: 2 dbuf x (A[256][64] + B[256][64]) bf16 = 128 KiB. Tile T lives in dbuf T&1.
// Per K-tile: 4 quadrant phases; per phase: {ds_reads, 1 half-tile stage, [waits],
// barrier, lgkmcnt(0), setprio(1), 8x mfma_32x32x16, setprio(0), barrier}.
// VMW(4) only at phases 4 and 8 (never drain to 0 in the main loop).
// Swizzle: LDS row r granule g holds global granule g^(r&7); reads XOR back.
// Rows are 128 B = 32 banks exactly -> row stride bank-invariant; per 16-lane
// beat reads hit 8 granules x 2 lanes = 2-way = free.
#define NT2 (K_DIM / 64)          // 64 K-tiles
#define DBUF_SHORTS 32768         // A 16384 + B 16384 shorts per dbuf

__global__ __launch_bounds__(512, 2) void gemm256_kernel(
    const unsigned short* __restrict__ xb, const unsigned short* __restrict__ wb,
    const float* __restrict__ bias, float* __restrict__ out) {
  __shared__ unsigned short lds[2 * DBUF_SHORTS];  // 128 KiB

  const int t = threadIdx.x;
  const int lane = t & 63;
  const int wid = t >> 6;          // 0..7
  const int wr = wid >> 2;         // 0..1  (M half)
  const int wc = wid & 3;          // 0..3  (N quarter)
  const int l31 = lane & 31;
  const int lhi = lane >> 5;

  // XCD-aware bijective swizzle; grid = 512 (divisible by 8)
  const int bid = blockIdx.x;
  const int swz = ((bid & 7) << 6) | (bid >> 3);
  const int bx = swz & 15;         // N/256 = 16
  const int by = swz >> 4;         // M/256 = 32
  const int brow = by * 256, bcol = bx * 256;

  // staging: half-tile = 128 rows x 64 k = 16 KiB = 512 thr x 2 gload16.
  // thread t, load l: row = (t>>3) + 64*l (+128*half), LDS granule = t&7,
  // sourcing global granule (t&7)^((t>>3)&7) (row&7-invariant across l, half).
  const int gsrc = (t & 7) ^ ((t >> 3) & 7);
  const unsigned short* gAs = xb + (size_t)(brow + (t >> 3)) * K_DIM + gsrc * 8;
  const unsigned short* gBs = wb + (size_t)(bcol + (t >> 3)) * K_DIM + gsrc * 8;

  // read-side: frag ks (k = ks*16 + 8*lhi + e) -> global granule ks*2+lhi,
  // stored at LDS granule (ks*2+lhi) ^ (row&7), row&7 = l31&7.
  const int r7 = l31 & 7;
  int gsk[4];
  #pragma unroll
  for (int ks = 0; ks < 4; ++ks) gsk[ks] = ((ks * 2 + lhi) ^ r7) * 8;
  const int aoff = (wr * 128 + l31) * 64;          // + mb*2048 (+ d*DBUF_SHORTS)
  const int boff = 16384 + (wc * 64 + l31) * 64;   // + nb*2048

  bf16x8 af[2][4], bfv[2][4];     // [mi|nb][ks]
  f32x16 acc[4][2] = {};          // [mb][nb]

  #define STG(isB, h, tile)                                                    \
    do {                                                                       \
      unsigned short* l_ = lds + ((tile) & 1) * DBUF_SHORTS + (isB) * 16384 +  \
                           (h) * 8192 + t * 8;                                 \
      const unsigned short* g_ = ((isB) ? gBs : gAs) +                         \
                                 (size_t)(h) * 128 * K_DIM + (size_t)(tile) * 64; \
      gload_lds16(g_, l_);                                                     \
      gload_lds16(g_ + (size_t)64 * K_DIM, l_ + 4096);                         \
    } while (0)

  #define RD_A(d, mi, mb)                                                      \
    { _Pragma("unroll")                                                        \
      for (int ks = 0; ks < 4; ++ks)                                           \
        af[mi][ks] = *(const bf16x8*)(lds + (d) * DBUF_SHORTS + aoff +         \
                                      (mb) * 2048 + gsk[ks]); }
  #define RD_B(d, nb)                                                          \
    { _Pragma("unroll")                                                        \
      for (int ks = 0; ks < 4; ++ks)                                           \
        bfv[nb][ks] = *(const bf16x8*)(lds + (d) * DBUF_SHORTS + boff +        \
                                       (nb) * 2048 + gsk[ks]); }

  // Quadrant (MP = m-pair 0/1, NB = n-block 0/1): 8 x mfma_32x32x16.
  #define MMQ(MP, NB)                                                          \
    __builtin_amdgcn_s_setprio(1);                                             \
    _Pragma("unroll")                                                          \
    for (int ks = 0; ks < 4; ++ks) {                                           \
      _Pragma("unroll")                                                        \
      for (int mi = 0; mi < 2; ++mi)                                           \
        acc[(MP) * 2 + mi][NB] = __builtin_amdgcn_mfma_f32_32x32x16_bf16(      \
            af[mi][ks], bfv[NB][ks], acc[(MP) * 2 + mi][NB], 0, 0, 0);         \
    }                                                                          \
    __builtin_amdgcn_s_setprio(0);

  // Phases. Stage expr passed as __VA_ARGS__ (contains commas).
  #define PH1(d, ...)                                                          \
    RD_A(d, 0, 0) RD_A(d, 1, 1) RD_B(d, 0)                                     \
    __VA_ARGS__;                                                               \
    asm volatile("s_waitcnt lgkmcnt(8)" ::: "memory");                         \
    RAW_BAR(); LGKM0(); MMQ(0, 0) RAW_BAR();
  #define PH2(d, ...)                                                          \
    RD_B(d, 1)                                                                 \
    __VA_ARGS__;                                                               \
    RAW_BAR(); LGKM0(); MMQ(0, 1) RAW_BAR();
  #define PH3(d, ...)                                                          \
    RD_A(d, 0, 2) RD_A(d, 1, 3)                                                \
    __VA_ARGS__;                                                               \
    RAW_BAR(); LGKM0(); MMQ(1, 0) RAW_BAR();
  #define PH4(wt, ...)                                                         \
    __VA_ARGS__;                                                               \
    wt;                                                                        \
    RAW_BAR(); MMQ(1, 1) RAW_BAR();

  // prologue: B0(0) B1(0) A0(0) A1(0) B0(1) B1(1) = 12 loads; retire tile 0.
  STG(1, 0, 0); STG(1, 1, 0); STG(0, 0, 0); STG(0, 1, 0);
  STG(1, 0, 1); STG(1, 1, 1);
  VMW(4);
  RAW_BAR();

  // steady: iter i computes tiles T0=2i (buf0, ph1-4) and T1=2i+1 (buf1, ph5-8).
  // VMW(4)@ph4 retires tile T1 (needed ph5); VMW(4)@ph8 retires T0+2 (next ph1).
  // Every stage targets a region whose last reader drained >=1 barrier earlier.
  for (int i = 0; i < NT2 / 2 - 1; ++i) {
    const int T1 = 2 * i + 1;
    PH1(0, STG(0, 0, T1))
    PH2(0, STG(0, 1, T1))
    PH3(0, STG(1, 0, T1 + 1))
    PH4(VMW(4), STG(1, 1, T1 + 1))
    PH1(1, STG(0, 0, T1 + 1))
    PH2(1, STG(0, 1, T1 + 1))
    PH3(1, STG(1, 0, T1 + 2))
    PH4(VMW(4), STG(1, 1, T1 + 2))
  }
  // last iter: tiles 62 (buf0), 63 (buf1); only A0/A1(63) remain to stage.
  PH1(0, STG(0, 0, NT2 - 1))
  PH2(0, STG(0, 1, NT2 - 1))
  PH3(0, NOOP)
  PH4(VMW(0), NOOP)
  PH1(1, NOOP)
  PH2(1, NOOP)
  PH3(1, NOOP)
  PH4(NOOP, NOOP)

  #undef STG
  #undef RD_A
  #undef RD_B
  #undef MMQ
  #undef PH1
  #undef PH2
  #undef PH3
  #undef PH4

  // epilogue: 32x32 C/D layout col = lane&31, row = (reg&3)+8*(reg>>2)+4*(lane>>5)
  // (verified correct in round 4, absmax 0.03125)
  #pragma unroll
  for (int nb = 0; nb < 2; ++nb) {
    const int col = bcol + wc * 64 + nb * 32 + l31;
    const float bv = bias[col];
    #pragma unroll
    for (int mb = 0; mb < 4; ++mb) {
      const int rbase = brow + wr * 128 + mb * 32 + 4 * lhi;
      #pragma unroll
      for (int r = 0; r < 16; ++r) {
        const int row = rbase + (r & 3) + 8 * (r >> 2);
        out[(size_t)row * N_DIM + col] = acc[mb][nb][r] + bv;
      }
    }
  }
}

// ---- fallback (ws too small): fused dequant 128^2 tile, correct but slower ----
__global__ __launch_bounds__(256) void gemm_fallback_kernel(
    const float* __restrict__ x, const int* __restrict__ qw,
    const float* __restrict__ scale, const float* __restrict__ zp,
    const float* __restrict__ bias, float* __restrict__ out) {
  __shared__ unsigned short lds_a[128 * 32];
  __shared__ unsigned short lds_b[128 * 32];
  const int t = threadIdx.x;
  const int lane = t & 63;
  const int wid = t >> 6;
  const int wr = wid >> 1, wc = wid & 1;
  const int fr = lane & 15, fq = lane >> 4;
  const int nwg = gridDim.x;
  const int cpx = nwg >> 3;
  const int bid = blockIdx.x;
  const int swz = (bid & 7) * cpx + (bid >> 3);
  const int bx = swz & 31, by = swz >> 5;
  const int brow = by * 128, bcol = bx * 128;
  const int r0 = t >> 2, c8 = (t & 3) * 8;
  f32x4 acc[4][4] = {};
  const float ss = scale[0], zs = zp[0];
  for (int kk = 0; kk < K_DIM; kk += 32) {
    ushort8 ua[2], ub[2];
    #pragma unroll
    for (int i = 0; i < 2; ++i) {
      const float* gp = x + (size_t)(brow + i * 64 + r0) * K_DIM + kk + c8;
      float4 v0 = *(const float4*)gp;
      float4 v1 = *(const float4*)(gp + 4);
      ua[i][0] = f2bf(v0.x); ua[i][1] = f2bf(v0.y); ua[i][2] = f2bf(v0.z); ua[i][3] = f2bf(v0.w);
      ua[i][4] = f2bf(v1.x); ua[i][5] = f2bf(v1.y); ua[i][6] = f2bf(v1.z); ua[i][7] = f2bf(v1.w);
      const int* qp = qw + (size_t)(bcol + i * 64 + r0) * K_DIM + kk + c8;
      int4 q0 = *(const int4*)qp;
      int4 q1 = *(const int4*)(qp + 4);
      ub[i][0] = f2bf(ss * ((float)q0.x - zs)); ub[i][1] = f2bf(ss * ((float)q0.y - zs));
      ub[i][2] = f2bf(ss * ((float)q0.z - zs)); ub[i][3] = f2bf(ss * ((float)q0.w - zs));
      ub[i][4] = f2bf(ss * ((float)q1.x - zs)); ub[i][5] = f2bf(ss * ((float)q1.y - zs));
      ub[i][6] = f2bf(ss * ((float)q1.z - zs)); ub[i][7] = f2bf(ss * ((float)q1.w - zs));
    }
    __syncthreads();
    #pragma unroll
    for (int i = 0; i < 2; ++i) {
      *(ushort8*)(lds_a + ((size_t)i * 256 + t) * 8) = ua[i];
      *(ushort8*)(lds_b + ((size_t)i * 256 + t) * 8) = ub[i];
    }
    __syncthreads();
    bf16x8 af[4], bfr[4];
    #pragma unroll
    for (int m = 0; m < 4; ++m)
      af[m] = *(const bf16x8*)(lds_a + (wr * 64 + m * 16 + fr) * 32 + fq * 8);
    #pragma unroll
    for (int n = 0; n < 4; ++n)
      bfr[n] = *(const bf16x8*)(lds_b + (wc * 64 + n * 16 + fr) * 32 + fq * 8);
    #pragma unroll
    for (int m = 0; m < 4; ++m)
      #pragma unroll
      for (int n = 0; n < 4; ++n)
        acc[m][n] = __builtin_amdgcn_mfma_f32_16x16x32_bf16(af[m], bfr[n], acc[m][n], 0, 0, 0);
  }
  #pragma unroll
  for (int n = 0; n < 4; ++n) {
    const int col = bcol + wc * 64 + n * 16 + fr;
    const float bv = bias[col];
    #pragma unroll
    for (int m = 0; m < 4; ++m) {
      const int rowb = brow + wr * 64 + m * 16 + fq * 4;
      #pragma unroll
      for (int j = 0; j < 4; ++j)
        out[(size_t)(rowb + j) * N_DIM + col] = acc[m][n][j] + bv;
    }
  }
}

extern "C" void kernel_launch(void* const* d_in, const int* in_sizes, int n_in,
                              void* d_out, int out_size, void* d_ws, size_t ws_size,
                              hipStream_t stream) {
  const float* x = (const float*)d_in[0];
  const int* qw = (const int*)d_in[1];
  const float* scale = (const float*)d_in[2];
  const float* zp = (const float*)d_in[3];
  const float* bias = (const float*)d_in[4];
  float* out = (float*)d_out;

  const size_t xb_bytes = (size_t)M_DIM * K_DIM * 2;
  const size_t wb_bytes = (size_t)N_DIM * K_DIM * 2;

  if (ws_size >= xb_bytes + wb_bytes) {
    unsigned short* xbuf = (unsigned short*)d_ws;
    unsigned short* wbuf = (unsigned short*)((char*)d_ws + xb_bytes);
    cvt_x_kernel<<<2048, 256, 0, stream>>>(x, xbuf, (long long)M_DIM * K_DIM / 8);
    dequant_w_kernel<<<2048, 256, 0, stream>>>(qw, scale, zp, wbuf, (long long)N_DIM * K_DIM / 8);
    const int grid = (M_DIM / 256) * (N_DIM / 256);  // 512, divisible by 8
    gemm256_kernel<<<grid, 512, 0, stream>>>(xbuf, wbuf, bias, out);
  } else {
    const int grid = (M_DIM / 128) * (N_DIM / 128);  // 2048
    gemm_fallback_kernel<<<grid, 256, 0, stream>>>(x, qw, scale, zp, bias, out);
  }
}

// Round 7
// 268.798 us; speedup vs baseline: 1.1665x; 1.1665x over previous
//
#include <hip/hip_runtime.h>
#include <hip/hip_bf16.h>
#include <stdint.h>

// x[4,2048,4096] f32, qweight[4096,4096] i32, scale/zp f32 scalars, bias[4096] f32
// out = x @ (scale*(q-zp))^T + bias : M=8192, N=4096, K=4096, f32 out.
#define M_DIM 8192
#define N_DIM 4096
#define K_DIM 4096

typedef __attribute__((ext_vector_type(8))) __bf16 bf16x8;
typedef __attribute__((ext_vector_type(4))) float f32x4;
typedef __attribute__((ext_vector_type(8))) unsigned short ushort8;

__device__ __forceinline__ unsigned short f2bf(float f) {
  union { float f; uint32_t u; } v; v.f = f;
  uint32_t u = v.u;
  return (unsigned short)((u + 0x7FFFu + ((u >> 16) & 1u)) >> 16);  // RNE
}

__device__ __forceinline__ void gload_lds16(const void* g, void* l) {
  __builtin_amdgcn_global_load_lds((const __attribute__((address_space(1))) void*)g,
                                   (__attribute__((address_space(3))) void*)l,
                                   16, 0, 0);
}

#define RAW_BAR() asm volatile("s_barrier" ::: "memory")
#define VMW(n) asm volatile("s_waitcnt vmcnt(" #n ")" ::: "memory")
#define LGKM0()                                        \
  do {                                                 \
    asm volatile("s_waitcnt lgkmcnt(0)" ::: "memory"); \
    __builtin_amdgcn_sched_barrier(0);                 \
  } while (0)
#define SBAR0() __builtin_amdgcn_sched_barrier(0)

// ---- fused prepack: x f32->bf16 and w dequant->bf16 in one launch ----
#define XN8 ((long long)M_DIM * K_DIM / 8)   // 4194304 granules of 8
#define WN8 ((long long)N_DIM * K_DIM / 8)   // 2097152

__global__ void prepack_kernel(const float* __restrict__ x, const int* __restrict__ q,
                               const float* __restrict__ scale, const float* __restrict__ zp,
                               unsigned short* __restrict__ xb, unsigned short* __restrict__ wb) {
  const float s = scale[0], z = zp[0];
  long long i = (long long)blockIdx.x * blockDim.x + threadIdx.x;
  const long long stride = (long long)gridDim.x * blockDim.x;
  for (; i < XN8 + WN8; i += stride) {
    ushort8 u;
    if (i < XN8) {
      const float4* p = (const float4*)x + i * 2;
      float4 a = p[0], b = p[1];
      u[0] = f2bf(a.x); u[1] = f2bf(a.y); u[2] = f2bf(a.z); u[3] = f2bf(a.w);
      u[4] = f2bf(b.x); u[5] = f2bf(b.y); u[6] = f2bf(b.z); u[7] = f2bf(b.w);
      *(ushort8*)(xb + i * 8) = u;
    } else {
      const long long j = i - XN8;
      const int4* p = (const int4*)q + j * 2;
      int4 a = p[0], b = p[1];
      u[0] = f2bf(s * ((float)a.x - z)); u[1] = f2bf(s * ((float)a.y - z));
      u[2] = f2bf(s * ((float)a.z - z)); u[3] = f2bf(s * ((float)a.w - z));
      u[4] = f2bf(s * ((float)b.x - z)); u[5] = f2bf(s * ((float)b.y - z));
      u[6] = f2bf(s * ((float)b.z - z)); u[7] = f2bf(s * ((float)b.w - z));
      *(ushort8*)(wb + j * 8) = u;
    }
  }
}

// ---- main GEMM: 256x256 tile, BK=64, 8 waves (2Mx4N, 128x64/wave), 16x16x32.
// Shadowed-read single-barrier schedule: each phase = {lgkmcnt(0) [waits reads
// issued LAST phase]; setprio; 16 MFMA; setprio; stage; [VMW(4)]; reads for
// NEXT quadrant; s_barrier}. Reads hide under the MFMA/stage window.
// Stages per iter (E=T0+2 buf0, O=T1+2 buf1): B(E)x2@PH3, A0(E)@PH4, A1(E)@PH5,
// B(O)x2@PH7, A(O)x2@PH8. VMW(4)@PH3 retires tile T1 (read from PH4);
// VMW(4)@PH7 retires tile E (read from PH8). Hazards: every stage >=2 phases
// after its region's last lgkm-waited read; fresh-tile reads after VMW+barrier.
// Swizzle: LDS row r granule g holds global granule g^(r&7); reads XOR back.
#define NT2 (K_DIM / 64)          // 64 K-tiles
#define DBUF_SHORTS 32768         // A 16384 + B 16384 shorts per dbuf

__global__ __launch_bounds__(512, 2) void gemm256_kernel(
    const unsigned short* __restrict__ xb, const unsigned short* __restrict__ wb,
    const float* __restrict__ bias, float* __restrict__ out) {
  __shared__ unsigned short lds[2 * DBUF_SHORTS];  // 128 KiB

  const int t = threadIdx.x;
  const int lane = t & 63;
  const int wid = t >> 6;          // 0..7
  const int wr = wid >> 2;         // 0..1  (M half)
  const int wc = wid & 3;          // 0..3  (N quarter)
  const int fr = lane & 15, fq = lane >> 4;
  const int fr7 = fr & 7;

  // XCD-aware bijective swizzle; grid = 512 (divisible by 8)
  const int bid = blockIdx.x;
  const int swz = ((bid & 7) << 6) | (bid >> 3);
  const int bx = swz & 15;         // N/256 = 16
  const int by = swz >> 4;         // M/256 = 32
  const int brow = by * 256, bcol = bx * 256;

  // staging: half-tile = 128 rows x 64 k = 16 KiB = 512 thr x 2 gload16.
  const int gsrc = (t & 7) ^ ((t >> 3) & 7);
  const unsigned short* gAs = xb + (size_t)(brow + (t >> 3)) * K_DIM + gsrc * 8;
  const unsigned short* gBs = wb + (size_t)(bcol + (t >> 3)) * K_DIM + gsrc * 8;

  // read-side swizzle
  const int gs0 = (fq ^ fr7) * 8;
  const int gs1 = ((4 | fq) ^ fr7) * 8;
  const int aoff = (wr * 128 + fr) * 64;          // + m*1024 (+ d*DBUF_SHORTS)
  const int boff = 16384 + (wc * 64 + fr) * 64;   // + n*1024

  bf16x8 af[8][2], bfv[4][2];
  f32x4 acc[8][4] = {};

  #define STG(isB, h, tile)                                                    \
    do {                                                                       \
      unsigned short* l_ = lds + ((tile) & 1) * DBUF_SHORTS + (isB) * 16384 +  \
                           (h) * 8192 + t * 8;                                 \
      const unsigned short* g_ = ((isB) ? gBs : gAs) +                         \
                                 (size_t)(h) * 128 * K_DIM + (size_t)(tile) * 64; \
      gload_lds16(g_, l_);                                                     \
      gload_lds16(g_ + (size_t)64 * K_DIM, l_ + 4096);                         \
    } while (0)

  #define RD_A(d, m)                                                           \
    af[m][0] = *(const bf16x8*)(lds + (d) * DBUF_SHORTS + aoff + (m) * 1024 + gs0); \
    af[m][1] = *(const bf16x8*)(lds + (d) * DBUF_SHORTS + aoff + (m) * 1024 + gs1);
  #define RD_B(d, n)                                                           \
    bfv[n][0] = *(const bf16x8*)(lds + (d) * DBUF_SHORTS + boff + (n) * 1024 + gs0); \
    bfv[n][1] = *(const bf16x8*)(lds + (d) * DBUF_SHORTS + boff + (n) * 1024 + gs1);

  #define RD_Q1(d) RD_A(d, 0) RD_A(d, 1) RD_A(d, 2) RD_A(d, 3) RD_B(d, 0) RD_B(d, 1)
  #define RD_Q2(d) RD_B(d, 2) RD_B(d, 3)
  #define RD_Q3(d) RD_A(d, 4) RD_A(d, 5) RD_A(d, 6) RD_A(d, 7)

  #define MMQ(MS, NS)                                                          \
    __builtin_amdgcn_s_setprio(1);                                             \
    _Pragma("unroll")                                                          \
    for (int ks = 0; ks < 2; ++ks) {                                           \
      _Pragma("unroll")                                                        \
      for (int m = 0; m < 4; ++m) {                                            \
        _Pragma("unroll")                                                      \
        for (int n = 0; n < 2; ++n)                                            \
          acc[MS + m][NS + n] = __builtin_amdgcn_mfma_f32_16x16x32_bf16(       \
              af[MS + m][ks], bfv[NS + n][ks], acc[MS + m][NS + n], 0, 0, 0);  \
      }                                                                        \
    }                                                                          \
    __builtin_amdgcn_s_setprio(0);                                             \
    SBAR0();

  // prologue: tile 0 then tile 1 fully staged; retire tile 0; pre-read Q1(0).
  STG(1, 0, 0); STG(1, 1, 0); STG(0, 0, 0); STG(0, 1, 0);
  STG(1, 0, 1); STG(1, 1, 1); STG(0, 0, 1); STG(0, 1, 1);
  VMW(8);
  RAW_BAR();
  RD_Q1(0)

  // steady: 31 iterations; iter i computes T0=2i (buf0) and T1=2i+1 (buf1),
  // stages E=2i+2 (buf0) and O=2i+3 (buf1).
  for (int i = 0; i < NT2 / 2 - 1; ++i) {
    const int E = 2 * i + 2, O = 2 * i + 3;
    // PH1: Q1(T0)
    LGKM0(); MMQ(0, 0) RD_Q2(0) RAW_BAR();
    // PH2: Q2(T0)
    LGKM0(); MMQ(0, 2) RD_Q3(0) RAW_BAR();
    // PH3: Q3(T0); stage B(E); retire tile T1
    LGKM0(); MMQ(4, 0) STG(1, 0, E); STG(1, 1, E); VMW(4); RAW_BAR();
    // PH4: Q4(T0); stage A0(E); read Q1(T1)
    MMQ(4, 2) STG(0, 0, E); RD_Q1(1) RAW_BAR();
    // PH5: Q1(T1); stage A1(E)
    LGKM0(); MMQ(0, 0) STG(0, 1, E); RD_Q2(1) RAW_BAR();
    // PH6: Q2(T1)
    LGKM0(); MMQ(0, 2) RD_Q3(1) RAW_BAR();
    // PH7: Q3(T1); stage B(O); retire tile E
    LGKM0(); MMQ(4, 0) STG(1, 0, O); STG(1, 1, O); VMW(4); RAW_BAR();
    // PH8: Q4(T1); stage A(O); read Q1(E)
    MMQ(4, 2) STG(0, 0, O); STG(0, 1, O); RD_Q1(0) RAW_BAR();
  }
  // tail: T0=62 (buf0), T1=63 (buf1); nothing left to stage.
  LGKM0(); MMQ(0, 0) RD_Q2(0) RAW_BAR();
  LGKM0(); MMQ(0, 2) RD_Q3(0) RAW_BAR();
  LGKM0(); MMQ(4, 0) VMW(0); RAW_BAR();
  MMQ(4, 2) RD_Q1(1) RAW_BAR();
  LGKM0(); MMQ(0, 0) RD_Q2(1) RAW_BAR();
  LGKM0(); MMQ(0, 2) RD_Q3(1) RAW_BAR();
  LGKM0(); MMQ(4, 0) RAW_BAR();
  MMQ(4, 2)

  #undef STG
  #undef RD_A
  #undef RD_B
  #undef RD_Q1
  #undef RD_Q2
  #undef RD_Q3
  #undef MMQ

  // epilogue: C/D layout col = lane&15, row = (lane>>4)*4 + j
  #pragma unroll
  for (int n = 0; n < 4; ++n) {
    const int col = bcol + wc * 64 + n * 16 + fr;
    const float bv = bias[col];
    #pragma unroll
    for (int m = 0; m < 8; ++m) {
      const int rowb = brow + wr * 128 + m * 16 + fq * 4;
      #pragma unroll
      for (int j = 0; j < 4; ++j)
        out[(size_t)(rowb + j) * N_DIM + col] = acc[m][n][j] + bv;
    }
  }
}

// ---- fallback (ws too small): fused dequant 128^2 tile, correct but slower ----
__global__ __launch_bounds__(256) void gemm_fallback_kernel(
    const float* __restrict__ x, const int* __restrict__ qw,
    const float* __restrict__ scale, const float* __restrict__ zp,
    const float* __restrict__ bias, float* __restrict__ out) {
  __shared__ unsigned short lds_a[128 * 32];
  __shared__ unsigned short lds_b[128 * 32];
  const int t = threadIdx.x;
  const int lane = t & 63;
  const int wid = t >> 6;
  const int wr = wid >> 1, wc = wid & 1;
  const int fr = lane & 15, fq = lane >> 4;
  const int nwg = gridDim.x;
  const int cpx = nwg >> 3;
  const int bid = blockIdx.x;
  const int swz = (bid & 7) * cpx + (bid >> 3);
  const int bx = swz & 31, by = swz >> 5;
  const int brow = by * 128, bcol = bx * 128;
  const int r0 = t >> 2, c8 = (t & 3) * 8;
  f32x4 acc[4][4] = {};
  const float ss = scale[0], zs = zp[0];
  for (int kk = 0; kk < K_DIM; kk += 32) {
    ushort8 ua[2], ub[2];
    #pragma unroll
    for (int i = 0; i < 2; ++i) {
      const float* gp = x + (size_t)(brow + i * 64 + r0) * K_DIM + kk + c8;
      float4 v0 = *(const float4*)gp;
      float4 v1 = *(const float4*)(gp + 4);
      ua[i][0] = f2bf(v0.x); ua[i][1] = f2bf(v0.y); ua[i][2] = f2bf(v0.z); ua[i][3] = f2bf(v0.w);
      ua[i][4] = f2bf(v1.x); ua[i][5] = f2bf(v1.y); ua[i][6] = f2bf(v1.z); ua[i][7] = f2bf(v1.w);
      const int* qp = qw + (size_t)(bcol + i * 64 + r0) * K_DIM + kk + c8;
      int4 q0 = *(const int4*)qp;
      int4 q1 = *(const int4*)(qp + 4);
      ub[i][0] = f2bf(ss * ((float)q0.x - zs)); ub[i][1] = f2bf(ss * ((float)q0.y - zs));
      ub[i][2] = f2bf(ss * ((float)q0.z - zs)); ub[i][3] = f2bf(ss * ((float)q0.w - zs));
      ub[i][4] = f2bf(ss * ((float)q1.x - zs)); ub[i][5] = f2bf(ss * ((float)q1.y - zs));
      ub[i][6] = f2bf(ss * ((float)q1.z - zs)); ub[i][7] = f2bf(ss * ((float)q1.w - zs));
    }
    __syncthreads();
    #pragma unroll
    for (int i = 0; i < 2; ++i) {
      *(ushort8*)(lds_a + ((size_t)i * 256 + t) * 8) = ua[i];
      *(ushort8*)(lds_b + ((size_t)i * 256 + t) * 8) = ub[i];
    }
    __syncthreads();
    bf16x8 af[4], bfr[4];
    #pragma unroll
    for (int m = 0; m < 4; ++m)
      af[m] = *(const bf16x8*)(lds_a + (wr * 64 + m * 16 + fr) * 32 + fq * 8);
    #pragma unroll
    for (int n = 0; n < 4; ++n)
      bfr[n] = *(const bf16x8*)(lds_b + (wc * 64 + n * 16 + fr) * 32 + fq * 8);
    #pragma unroll
    for (int m = 0; m < 4; ++m)
      #pragma unroll
      for (int n = 0; n < 4; ++n)
        acc[m][n] = __builtin_amdgcn_mfma_f32_16x16x32_bf16(af[m], bfr[n], acc[m][n], 0, 0, 0);
  }
  #pragma unroll
  for (int n = 0; n < 4; ++n) {
    const int col = bcol + wc * 64 + n * 16 + fr;
    const float bv = bias[col];
    #pragma unroll
    for (int m = 0; m < 4; ++m) {
      const int rowb = brow + wr * 64 + m * 16 + fq * 4;
      #pragma unroll
      for (int j = 0; j < 4; ++j)
        out[(size_t)(rowb + j) * N_DIM + col] = acc[m][n][j] + bv;
    }
  }
}

extern "C" void kernel_launch(void* const* d_in, const int* in_sizes, int n_in,
                              void* d_out, int out_size, void* d_ws, size_t ws_size,
                              hipStream_t stream) {
  const float* x = (const float*)d_in[0];
  const int* qw = (const int*)d_in[1];
  const float* scale = (const float*)d_in[2];
  const float* zp = (const float*)d_in[3];
  const float* bias = (const float*)d_in[4];
  float* out = (float*)d_out;

  const size_t xb_bytes = (size_t)M_DIM * K_DIM * 2;
  const size_t wb_bytes = (size_t)N_DIM * K_DIM * 2;

  if (ws_size >= xb_bytes + wb_bytes) {
    unsigned short* xbuf = (unsigned short*)d_ws;
    unsigned short* wbuf = (unsigned short*)((char*)d_ws + xb_bytes);
    prepack_kernel<<<2048, 256, 0, stream>>>(x, qw, scale, zp, xbuf, wbuf);
    const int grid = (M_DIM / 256) * (N_DIM / 256);  // 512, divisible by 8
    gemm256_kernel<<<grid, 512, 0, stream>>>(xbuf, wbuf, bias, out);
  } else {
    const int grid = (M_DIM / 128) * (N_DIM / 128);  // 2048
    gemm_fallback_kernel<<<grid, 256, 0, stream>>>(x, qw, scale, zp, bias, out);
  }
}

// Round 8
// 186.214 us; speedup vs baseline: 1.6838x; 1.4435x over previous
//
#include <hip/hip_runtime.h>
#include <hip/hip_bf16.h>
#include <stdint.h>

// x[4,2048,4096] f32, qweight[4096,4096] i32, scale/zp f32 scalars, bias[4096] f32
// out = x @ (scale*(q-zp))^T + bias : M=8192, N=4096, K=4096, f32 out.
// i8 path: W = s(q-128) + s(128-zp); x ~= rowscale * qx (i8).
// out = (rowscale*s) * (qx @ (q-128)^T)_i32  +  s(128-zp)*rowsum(x)  + bias.
#define M_DIM 8192
#define N_DIM 4096
#define K_DIM 4096

typedef __attribute__((ext_vector_type(4))) int i32x4;
typedef __attribute__((ext_vector_type(8))) __bf16 bf16x8;
typedef __attribute__((ext_vector_type(4))) float f32x4;
typedef __attribute__((ext_vector_type(8))) unsigned short ushort8;

__device__ __forceinline__ unsigned short f2bf(float f) {
  union { float f; uint32_t u; } v; v.f = f;
  uint32_t u = v.u;
  return (unsigned short)((u + 0x7FFFu + ((u >> 16) & 1u)) >> 16);  // RNE
}

__device__ __forceinline__ void gload_lds16(const void* g, void* l) {
  __builtin_amdgcn_global_load_lds((const __attribute__((address_space(1))) void*)g,
                                   (__attribute__((address_space(3))) void*)l,
                                   16, 0, 0);
}

#define RAW_BAR() asm volatile("s_barrier" ::: "memory")
#define VMW(n) asm volatile("s_waitcnt vmcnt(" #n ")" ::: "memory")
#define LGKM0()                                        \
  do {                                                 \
    asm volatile("s_waitcnt lgkmcnt(0)" ::: "memory"); \
    __builtin_amdgcn_sched_barrier(0);                 \
  } while (0)
#define SBAR0() __builtin_amdgcn_sched_barrier(0)

// ---- prepack 1: x -> per-row i8 (rowscale), rsw[row]=rowscale*s, corr[row]=s(128-zp)*rowsum
__global__ __launch_bounds__(256) void prepx_kernel(
    const float* __restrict__ x, const float* __restrict__ scale,
    const float* __restrict__ zp, char* __restrict__ xq,
    float* __restrict__ rsw, float* __restrict__ corr) {
  const int row = blockIdx.x;
  const int t = threadIdx.x;
  const float4* xr = (const float4*)(x + (size_t)row * K_DIM);
  float4 v[4];
  float mx = 0.f;
  #pragma unroll
  for (int i = 0; i < 4; ++i) {
    v[i] = xr[i * 256 + t];
    mx = fmaxf(mx, fmaxf(fmaxf(fabsf(v[i].x), fabsf(v[i].y)),
                         fmaxf(fabsf(v[i].z), fabsf(v[i].w))));
  }
  __shared__ float redm[4], reds[4];
  #pragma unroll
  for (int off = 32; off; off >>= 1) mx = fmaxf(mx, __shfl_xor(mx, off));
  if ((t & 63) == 0) redm[t >> 6] = mx;
  __syncthreads();
  mx = fmaxf(fmaxf(redm[0], redm[1]), fmaxf(redm[2], redm[3]));
  mx = fmaxf(mx, 1e-20f);
  const float inv = 127.f / mx;
  float sum = 0.f;
  int* xqo = (int*)xq + (size_t)row * (K_DIM / 4);
  #pragma unroll
  for (int i = 0; i < 4; ++i) {
    sum += v[i].x + v[i].y + v[i].z + v[i].w;
    int q0 = (int)rintf(v[i].x * inv), q1 = (int)rintf(v[i].y * inv);
    int q2 = (int)rintf(v[i].z * inv), q3 = (int)rintf(v[i].w * inv);
    xqo[i * 256 + t] = (q0 & 255) | ((q1 & 255) << 8) | ((q2 & 255) << 16) | (q3 << 24);
  }
  #pragma unroll
  for (int off = 32; off; off >>= 1) sum += __shfl_xor(sum, off);
  if ((t & 63) == 0) reds[t >> 6] = sum;
  __syncthreads();
  if (t == 0) {
    const float sw = scale[0], zw = zp[0];
    rsw[row] = (mx / 127.f) * sw;
    corr[row] = sw * (128.f - zw) * (reds[0] + reds[1] + reds[2] + reds[3]);
  }
}

// ---- prepack 2: wq = q - 128 (i8, exact) ----
__global__ void prepw_kernel(const int* __restrict__ q, char* __restrict__ wq) {
  const long long n4 = (long long)N_DIM * K_DIM / 4;
  long long i = (long long)blockIdx.x * blockDim.x + threadIdx.x;
  const long long stride = (long long)gridDim.x * blockDim.x;
  int* wo = (int*)wq;
  for (; i < n4; i += stride) {
    const int4 a = ((const int4*)q)[i];
    wo[i] = ((a.x - 128) & 255) | (((a.y - 128) & 255) << 8) |
            (((a.z - 128) & 255) << 16) | ((a.w - 128) << 24);
  }
}

// ---- main GEMM: i8, 256x256 tile, BK=64, 8 waves (2Mx4N, 128x64/wave),
// mfma_i32_16x16x64_i8 (one K-step per MFMA). 3 LDS buffers (tile X -> buf X%3),
// 2 phases per K-tile, 2 barriers/K-tile, counted VMW(2) (never 0 in main loop).
// Per phase: {lgkmcnt(0) [reads issued last phase]; issue next reads; 16 MFMA;
// stage; [VMW]; barrier}. A staged in P_b, B in P_a (hazard-audited).
// Swizzle (round-2-proven geometry): 64B rows, 16B granules, g' = g ^ ((row>>1)&3).
#define NTILE (K_DIM / 64)        // 64 K-tiles
#define BUFB 32768                // per buf: A 16 KB + B 16 KB

__global__ __launch_bounds__(512, 2) void gemm256_i8_kernel(
    const char* __restrict__ xq, const char* __restrict__ wq,
    const float* __restrict__ rsw, const float* __restrict__ corr,
    const float* __restrict__ bias, float* __restrict__ out) {
  __shared__ char lds[3 * BUFB];  // 96 KiB

  const int t = threadIdx.x;
  const int lane = t & 63;
  const int wid = t >> 6;          // 0..7
  const int wr = wid >> 2;         // 0..1  (M half)
  const int wc = wid & 3;          // 0..3  (N quarter)
  const int fr = lane & 15, fq = lane >> 4;

  // XCD-aware bijective swizzle; grid = 512 (divisible by 8)
  const int bid = blockIdx.x;
  const int swz = ((bid & 7) << 6) | (bid >> 3);
  const int bx = swz & 15;         // N/256 = 16
  const int by = swz >> 4;         // M/256 = 32
  const int brow = by * 256, bcol = bx * 256;

  // staging: half-tile = 128 rows x 64 B = 8 KB = 512 thr x 1 gload16.
  // thread t: row = t>>2, LDS granule t&3 holds global granule (t&3)^((row>>1)&3).
  const int gsrc = (t & 3) ^ ((t >> 3) & 3);
  const char* gAs = xq + (size_t)(brow + (t >> 2)) * K_DIM + gsrc * 16;
  const char* gBs = wq + (size_t)(bcol + (t >> 2)) * K_DIM + gsrc * 16;

  // read-side: lane (fr,fq) wants global granule fq of its row -> LDS granule fq^((fr>>1)&3)
  const int gsel16 = (fq ^ ((fr >> 1) & 3)) * 16;
  const int arow = (wr * 128 + fr) * 64;           // + m*1024, byte offsets
  const int brow_o = 16384 + (wc * 64 + fr) * 64;  // + n*1024

  i32x4 af[8], bfv[2][4];
  i32x4 acc[8][4] = {};

  #define LD_A(b, m) (*(const i32x4*)(lds + (b) * BUFB + arow + (m) * 1024 + gsel16))
  #define LD_B(b, n) (*(const i32x4*)(lds + (b) * BUFB + brow_o + (n) * 1024 + gsel16))

  #define RD_H1(b, p)                                                          \
    { af[0] = LD_A(b, 0); af[1] = LD_A(b, 1); af[2] = LD_A(b, 2);              \
      af[3] = LD_A(b, 3);                                                      \
      bfv[p][0] = LD_B(b, 0); bfv[p][1] = LD_B(b, 1);                          \
      bfv[p][2] = LD_B(b, 2); bfv[p][3] = LD_B(b, 3); }
  #define RD_H2(b)                                                             \
    { af[4] = LD_A(b, 4); af[5] = LD_A(b, 5); af[6] = LD_A(b, 6);              \
      af[7] = LD_A(b, 7); }

  #define STG(isB, h, tile, b)                                                 \
    do {                                                                       \
      char* l_ = lds + (b) * BUFB + (isB) * 16384 + (h) * 8192 + t * 16;       \
      const char* g_ = ((isB) ? gBs : gAs) + (size_t)(h) * 128 * K_DIM +       \
                       (size_t)(tile) * 64;                                    \
      gload_lds16(g_, l_);                                                     \
    } while (0)

  #define MMQ(MS, p)                                                           \
    __builtin_amdgcn_s_setprio(1);                                             \
    _Pragma("unroll")                                                          \
    for (int m = 0; m < 4; ++m) {                                              \
      _Pragma("unroll")                                                        \
      for (int n = 0; n < 4; ++n)                                              \
        acc[MS + m][n] = __builtin_amdgcn_mfma_i32_16x16x64_i8(                \
            af[MS + m], bfv[p][n], acc[MS + m][n], 0, 0, 0);                   \
    }                                                                          \
    __builtin_amdgcn_s_setprio(0);                                             \
    SBAR0();

  // P_a(X): lgkm-wait H1(X) [issued last phase]; issue H2(X); MFMA m0-3;
  //         stage B(X+2); VMW; barrier.   (publishes tile X+1)
  #define PH_A(b, p, STGB_, WT_)                                               \
    LGKM0(); RD_H2(b) MMQ(0, p) STGB_; WT_; RAW_BAR();
  // P_b(X): lgkm-wait H2(X); issue H1(X+1) -> bfv[p^1], af[0..3]; MFMA m4-7;
  //         stage A(X+2); barrier.
  #define PH_B(b, p, STGA_, RDN_)                                              \
    LGKM0(); RDN_ MMQ(4, p) STGA_; RAW_BAR();

  #define TILE_FULL(b, BN, B2, p, np, Xp2)                                     \
    PH_A(b, p, { STG(1, 0, Xp2, B2); STG(1, 1, Xp2, B2); }, VMW(2))            \
    PH_B(b, p, { STG(0, 0, Xp2, B2); STG(0, 1, Xp2, B2); }, RD_H1(BN, np))

  // prologue: stage tiles 0 (buf0) and 1 (buf1); publish tile 0; pre-read H1(0).
  STG(1, 0, 0, 0); STG(1, 1, 0, 0); STG(0, 0, 0, 0); STG(0, 1, 0, 0);
  STG(1, 0, 1, 1); STG(1, 1, 1, 1); STG(0, 0, 1, 1); STG(0, 1, 1, 1);
  VMW(4);
  RAW_BAR();
  RD_H1(0, 0)

  // steady: X = 6*jj .. 6*jj+5, bufs 0,1,2,0,1,2, parity 0,1,0,1,0,1.
  // VMW(2)@P_a(X) retires B(X+1),A(X+1) (publish X+1), leaves B(X+2) in flight.
  // Stage hazards: B(X+2) over buf(X-1)-B whose reads lgkm'd @P_a(X-1) (bar-sep);
  // A(X+2)@P_b over buf(X-1)-A whose af4-7 lgkm'd @P_b(X-1) (bar-sep).
  for (int jj = 0; jj < 10; ++jj) {
    const int X = 6 * jj;
    TILE_FULL(0, 1, 2, 0, 1, X + 2)
    TILE_FULL(1, 2, 0, 1, 0, X + 3)
    TILE_FULL(2, 0, 1, 0, 1, X + 4)
    TILE_FULL(0, 1, 2, 1, 0, X + 5)
    TILE_FULL(1, 2, 0, 0, 1, X + 6)
    TILE_FULL(2, 0, 1, 1, 0, X + 7)
  }
  // X=60 (buf0,p0): stages 62->buf2.  X=61 (buf1,p1): stages 63->buf0.
  TILE_FULL(0, 1, 2, 0, 1, 62)
  TILE_FULL(1, 2, 0, 1, 0, 63)
  // X=62 (buf2,p0): tail — VMW(0) publishes tile 63.
  PH_A(2, 0, {}, VMW(0))
  PH_B(2, 0, {}, RD_H1(0, 1))
  // X=63 (buf0,p1): final.
  PH_A(0, 1, {}, {})
  LGKM0();
  MMQ(4, 1)

  #undef LD_A
  #undef LD_B
  #undef RD_H1
  #undef RD_H2
  #undef STG
  #undef MMQ
  #undef PH_A
  #undef PH_B
  #undef TILE_FULL

  // epilogue: C/D layout col = lane&15, row = (lane>>4)*4 + j (shape-determined,
  // dtype-independent). out = acc*rsw[row] + corr[row] + bias[col].
  float bv[4];
  #pragma unroll
  for (int n = 0; n < 4; ++n) bv[n] = bias[bcol + wc * 64 + n * 16 + fr];
  #pragma unroll
  for (int m = 0; m < 8; ++m) {
    #pragma unroll
    for (int j = 0; j < 4; ++j) {
      const int row = brow + wr * 128 + m * 16 + fq * 4 + j;
      const float rs_ = rsw[row], co_ = corr[row];
      #pragma unroll
      for (int n = 0; n < 4; ++n) {
        const int col = bcol + wc * 64 + n * 16 + fr;
        out[(size_t)row * N_DIM + col] = (float)acc[m][n][j] * rs_ + co_ + bv[n];
      }
    }
  }
}

// ---- fallback (ws too small): fused dequant bf16 128^2 tile, correct but slower ----
__global__ __launch_bounds__(256) void gemm_fallback_kernel(
    const float* __restrict__ x, const int* __restrict__ qw,
    const float* __restrict__ scale, const float* __restrict__ zp,
    const float* __restrict__ bias, float* __restrict__ out) {
  __shared__ unsigned short lds_a[128 * 32];
  __shared__ unsigned short lds_b[128 * 32];
  const int t = threadIdx.x;
  const int lane = t & 63;
  const int wid = t >> 6;
  const int wr = wid >> 1, wc = wid & 1;
  const int fr = lane & 15, fq = lane >> 4;
  const int nwg = gridDim.x;
  const int cpx = nwg >> 3;
  const int bid = blockIdx.x;
  const int swz = (bid & 7) * cpx + (bid >> 3);
  const int bx = swz & 31, by = swz >> 5;
  const int brow = by * 128, bcol = bx * 128;
  const int r0 = t >> 2, c8 = (t & 3) * 8;
  f32x4 acc[4][4] = {};
  const float ss = scale[0], zs = zp[0];
  for (int kk = 0; kk < K_DIM; kk += 32) {
    ushort8 ua[2], ub[2];
    #pragma unroll
    for (int i = 0; i < 2; ++i) {
      const float* gp = x + (size_t)(brow + i * 64 + r0) * K_DIM + kk + c8;
      float4 v0 = *(const float4*)gp;
      float4 v1 = *(const float4*)(gp + 4);
      ua[i][0] = f2bf(v0.x); ua[i][1] = f2bf(v0.y); ua[i][2] = f2bf(v0.z); ua[i][3] = f2bf(v0.w);
      ua[i][4] = f2bf(v1.x); ua[i][5] = f2bf(v1.y); ua[i][6] = f2bf(v1.z); ua[i][7] = f2bf(v1.w);
      const int* qp = qw + (size_t)(bcol + i * 64 + r0) * K_DIM + kk + c8;
      int4 q0 = *(const int4*)qp;
      int4 q1 = *(const int4*)(qp + 4);
      ub[i][0] = f2bf(ss * ((float)q0.x - zs)); ub[i][1] = f2bf(ss * ((float)q0.y - zs));
      ub[i][2] = f2bf(ss * ((float)q0.z - zs)); ub[i][3] = f2bf(ss * ((float)q0.w - zs));
      ub[i][4] = f2bf(ss * ((float)q1.x - zs)); ub[i][5] = f2bf(ss * ((float)q1.y - zs));
      ub[i][6] = f2bf(ss * ((float)q1.z - zs)); ub[i][7] = f2bf(ss * ((float)q1.w - zs));
    }
    __syncthreads();
    #pragma unroll
    for (int i = 0; i < 2; ++i) {
      *(ushort8*)(lds_a + ((size_t)i * 256 + t) * 8) = ua[i];
      *(ushort8*)(lds_b + ((size_t)i * 256 + t) * 8) = ub[i];
    }
    __syncthreads();
    bf16x8 af[4], bfr[4];
    #pragma unroll
    for (int m = 0; m < 4; ++m)
      af[m] = *(const bf16x8*)(lds_a + (wr * 64 + m * 16 + fr) * 32 + fq * 8);
    #pragma unroll
    for (int n = 0; n < 4; ++n)
      bfr[n] = *(const bf16x8*)(lds_b + (wc * 64 + n * 16 + fr) * 32 + fq * 8);
    #pragma unroll
    for (int m = 0; m < 4; ++m)
      #pragma unroll
      for (int n = 0; n < 4; ++n)
        acc[m][n] = __builtin_amdgcn_mfma_f32_16x16x32_bf16(af[m], bfr[n], acc[m][n], 0, 0, 0);
  }
  #pragma unroll
  for (int n = 0; n < 4; ++n) {
    const int col = bcol + wc * 64 + n * 16 + fr;
    const float bvv = bias[col];
    #pragma unroll
    for (int m = 0; m < 4; ++m) {
      const int rowb = brow + wr * 64 + m * 16 + fq * 4;
      #pragma unroll
      for (int j = 0; j < 4; ++j)
        out[(size_t)(rowb + j) * N_DIM + col] = acc[m][n][j] + bvv;
    }
  }
}

extern "C" void kernel_launch(void* const* d_in, const int* in_sizes, int n_in,
                              void* d_out, int out_size, void* d_ws, size_t ws_size,
                              hipStream_t stream) {
  const float* x = (const float*)d_in[0];
  const int* qw = (const int*)d_in[1];
  const float* scale = (const float*)d_in[2];
  const float* zp = (const float*)d_in[3];
  const float* bias = (const float*)d_in[4];
  float* out = (float*)d_out;

  const size_t xq_bytes = (size_t)M_DIM * K_DIM;          // 32 MB
  const size_t wq_bytes = (size_t)N_DIM * K_DIM;          // 16 MB
  const size_t rsw_bytes = (size_t)M_DIM * 4;             // 32 KB
  const size_t need = xq_bytes + wq_bytes + 2 * rsw_bytes;

  if (ws_size >= need) {
    char* xq = (char*)d_ws;
    char* wq = (char*)d_ws + xq_bytes;
    float* rsw = (float*)((char*)d_ws + xq_bytes + wq_bytes);
    float* corr = rsw + M_DIM;
    prepx_kernel<<<M_DIM, 256, 0, stream>>>(x, scale, zp, xq, rsw, corr);
    prepw_kernel<<<2048, 256, 0, stream>>>(qw, wq);
    const int grid = (M_DIM / 256) * (N_DIM / 256);  // 512, divisible by 8
    gemm256_i8_kernel<<<grid, 512, 0, stream>>>(xq, wq, rsw, corr, bias, out);
  } else {
    const int grid = (M_DIM / 128) * (N_DIM / 128);  // 2048
    gemm_fallback_kernel<<<grid, 256, 0, stream>>>(x, qw, scale, zp, bias, out);
  }
}